// Round 1
// baseline (45.961 us; speedup 1.0000x reference)
//
#include <hip/hip_runtime.h>

// Problem: out[a,j,r,b] = x[a,(d-j)%d,r,b] with d=4, index=2, L=6
// x: [N=4096, B=8192] float32 row-major. left=16, d=4, right=64.
// Row mapping: src_row = row + delta*64, delta = {0,+2,0,-2}[(row>>6)&3].
// Pure permuted copy: 128 MiB in + 128 MiB out -> memory-bound, ~43us floor.

#define B_COLS   8192
#define B_COLS4  2048          // B/4 float4 per row
#define LOG_B4   11            // log2(2048)
#define N_ROWS   4096
#define TOTAL4   (N_ROWS * B_COLS4)   // 8,388,608 float4 elements

__global__ __launch_bounds__(256) void perm_copy_kernel(
        const float4* __restrict__ x, float4* __restrict__ out) {
    int stride = gridDim.x * blockDim.x;
    for (int n = blockIdx.x * blockDim.x + threadIdx.x; n < TOTAL4; n += stride) {
        int row  = n >> LOG_B4;
        int col  = n & (B_COLS4 - 1);
        int j    = (row >> 6) & 3;          // wire digit of this output row
        int i    = (4 - j) & 3;             // source wire digit
        int src_row = row + ((i - j) << 6); // delta * right(=64)
        out[n] = x[(src_row << LOG_B4) | col];
    }
}

extern "C" void kernel_launch(void* const* d_in, const int* in_sizes, int n_in,
                              void* d_out, int out_size, void* d_ws, size_t ws_size,
                              hipStream_t stream) {
    const float4* x   = (const float4*)d_in[0];
    float4*       out = (float4*)d_out;
    // 2048 blocks x 256 threads, grid-stride: 16 float4 per thread.
    perm_copy_kernel<<<2048, 256, 0, stream>>>(x, out);
}